// Round 8
// baseline (84.859 us; speedup 1.0000x reference)
//
#include <hip/hip_runtime.h>
#include <hip/hip_bf16.h>

// Sizes fixed by the reference
#define V 50000
#define D 256
#define B 256
#define C 10
#define TWO_D 512
#define VBLK 32
#define NGI 521                        // tile-groups; 521*3 = 1563 tiles exactly
#define TPB 3                          // tiles per wave
#define NBLK_OUT NGI
#define MPAD 4096                      // 256 b * 16 (c padded 10 -> 16)

typedef __bf16 bf16x8 __attribute__((ext_vector_type(8)));
typedef float f32x4 __attribute__((ext_vector_type(4)));
typedef unsigned short ushort_t;
typedef unsigned int uint_t;

__device__ inline ushort_t f2bf(float f) {
    uint_t u = __builtin_bit_cast(uint_t, f);
    uint_t r = (u + 0x7FFFu + ((u >> 16) & 1u)) >> 16;
    return (ushort_t)r;
}

__device__ inline float softplus_f(float x) {
    return (x > 0.f) ? (x + log1pf(__expf(-x))) : log1pf(__expf(x));
}

__device__ inline float wave_reduce(float v) {
    #pragma unroll
    for (int m = 1; m < 64; m <<= 1) v += __shfl_xor(v, m);
    return v;
}

// counted vmcnt wait (inline asm, memory clobber pins load issue order)
#define SWAIT(N) do { \
    asm volatile("s_waitcnt vmcnt(" #N ")" ::: "memory"); \
    __builtin_amdgcn_sched_barrier(0); \
} while (0)

// ---------------------------------------------------------------------------
// K0: build X_bf [4096 x 512]: row m = b*16+c -> [center_b | ctx_{b,c}] bf16.
// ---------------------------------------------------------------------------
__global__ __launch_bounds__(256) void k0_gather(
    const int* __restrict__ center_id, const int* __restrict__ context_ids,
    const float* __restrict__ embeddings, ushort_t* __restrict__ xbf)
{
    const int idx = blockIdx.x * 256 + threadIdx.x;  // float4 index
    const int m = idx >> 7;
    const int q = idx & 127;
    const int k = q * 4;
    const int b = m >> 4, c = m & 15;
    ushort4 o;
    if (k < D) {
        const float4 v = *(const float4*)(embeddings + center_id[b] * D + k);
        o.x = f2bf(v.x); o.y = f2bf(v.y); o.z = f2bf(v.z); o.w = f2bf(v.w);
    } else if (c < C) {
        const float4 v = *(const float4*)(embeddings + context_ids[b * C + c] * D + (k - D));
        o.x = f2bf(v.x); o.y = f2bf(v.y); o.z = f2bf(v.z); o.w = f2bf(v.w);
    } else {
        o.x = 0; o.y = 0; o.z = 0; o.w = 0;
    }
    *(ushort4*)(xbf + idx * 4) = o;
}

// ---------------------------------------------------------------------------
// K_enc: MFMA GEMM + fused bias/relu/c-sum -> h_bf[b][e]. (unchanged, proven)
// ---------------------------------------------------------------------------
__global__ __launch_bounds__(256) void k_enc(
    const float* __restrict__ enc_W, const float* __restrict__ enc_b,
    const ushort_t* __restrict__ xbf, ushort_t* __restrict__ h_bf)
{
    __shared__ __align__(16) ushort_t wt[2][64 * 40];
    const int tid = threadIdx.x;
    const int mblk = blockIdx.x & 63;
    const int nblk = blockIdx.x >> 6;
    const int n0 = nblk * 64;
    const int wid = tid >> 6, lane = tid & 63;
    const int l15 = lane & 15, g = lane >> 4;

    const int r0 = tid >> 3, kq = tid & 7, r1 = r0 + 32;
    const float* src0 = enc_W + (n0 + r0) * TWO_D + kq * 4;
    const float* src1 = enc_W + (n0 + r1) * TWO_D + kq * 4;
    const int dst0 = r0 * 40 + kq * 4;
    const int dst1 = r1 * 40 + kq * 4;

    {
        const float4 na = *(const float4*)(src0);
        const float4 nb = *(const float4*)(src1);
        ushort4 pa, pb;
        pa.x = f2bf(na.x); pa.y = f2bf(na.y); pa.z = f2bf(na.z); pa.w = f2bf(na.w);
        pb.x = f2bf(nb.x); pb.y = f2bf(nb.y); pb.z = f2bf(nb.z); pb.w = f2bf(nb.w);
        *(ushort4*)(&wt[0][dst0]) = pa;
        *(ushort4*)(&wt[0][dst1]) = pb;
    }
    __syncthreads();

    const int rowA = mblk * 64 + wid * 16 + l15;
    f32x4 acc[4] = {};
    #pragma unroll 1
    for (int kk = 0; kk < 16; ++kk) {
        const int cur = kk & 1, nxt = cur ^ 1;
        float4 na, nb;
        if (kk < 15) {
            na = *(const float4*)(src0 + (kk + 1) * 32);
            nb = *(const float4*)(src1 + (kk + 1) * 32);
        }
        const bf16x8 A = *(const bf16x8*)(xbf + rowA * TWO_D + kk * 32 + g * 8);
        bf16x8 Bf[4];
        #pragma unroll
        for (int vt = 0; vt < 4; ++vt)
            Bf[vt] = *(const bf16x8*)(&wt[cur][(vt * 16 + l15) * 40 + g * 8]);
        #pragma unroll
        for (int vt = 0; vt < 4; ++vt)
            acc[vt] = __builtin_amdgcn_mfma_f32_16x16x32_bf16(A, Bf[vt], acc[vt], 0, 0, 0);
        if (kk < 15) {
            ushort4 pa, pb;
            pa.x = f2bf(na.x); pa.y = f2bf(na.y); pa.z = f2bf(na.z); pa.w = f2bf(na.w);
            pb.x = f2bf(nb.x); pb.y = f2bf(nb.y); pb.z = f2bf(nb.z); pb.w = f2bf(nb.w);
            *(ushort4*)(&wt[nxt][dst0]) = pa;
            *(ushort4*)(&wt[nxt][dst1]) = pb;
        }
        __syncthreads();
    }

    const int b = mblk * 4 + wid;
    #pragma unroll
    for (int vt = 0; vt < 4; ++vt) {
        const int j = n0 + vt * 16 + l15;
        const float bias = enc_b[j];
        float s = 0.f;
        #pragma unroll
        for (int r = 0; r < 4; ++r) {
            const int c = g * 4 + r;
            const float vv = acc[vt][r] + bias;
            s += (c < C) ? fmaxf(vv, 0.f) : 0.f;
        }
        s += __shfl_xor(s, 16);
        s += __shfl_xor(s, 32);
        if (g == 0) h_bf[b * TWO_D + j] = f2bf(s);
    }
}

// ---------------------------------------------------------------------------
// K_heads: MFMA GEMM mv = h @ [mean_W; var_W]^T + bias. (unchanged, proven)
// ---------------------------------------------------------------------------
__global__ __launch_bounds__(256) void k_heads(
    const float* __restrict__ mean_W, const float* __restrict__ mean_b,
    const float* __restrict__ var_W, const float* __restrict__ var_b,
    const ushort_t* __restrict__ h_bf, float* __restrict__ mv)
{
    __shared__ __align__(16) ushort_t wt[2][64 * 40];
    const int tid = threadIdx.x;
    const int mblk = blockIdx.x & 3;
    const int nblk = blockIdx.x >> 2;
    const int n0 = nblk * 64;
    const float* Wsrc = (nblk < 4) ? mean_W : var_W;
    const float* bsrc = (nblk < 4) ? mean_b : var_b;
    const int nloc = (nblk & 3) * 64;
    const int wid = tid >> 6, lane = tid & 63;
    const int l15 = lane & 15, g = lane >> 4;

    const int r0 = tid >> 3, kq = tid & 7, r1 = r0 + 32;
    const float* src0 = Wsrc + (nloc + r0) * TWO_D + kq * 4;
    const float* src1 = Wsrc + (nloc + r1) * TWO_D + kq * 4;
    const int dst0 = r0 * 40 + kq * 4;
    const int dst1 = r1 * 40 + kq * 4;

    {
        const float4 na = *(const float4*)(src0);
        const float4 nb = *(const float4*)(src1);
        ushort4 pa, pb;
        pa.x = f2bf(na.x); pa.y = f2bf(na.y); pa.z = f2bf(na.z); pa.w = f2bf(na.w);
        pb.x = f2bf(nb.x); pb.y = f2bf(nb.y); pb.z = f2bf(nb.z); pb.w = f2bf(nb.w);
        *(ushort4*)(&wt[0][dst0]) = pa;
        *(ushort4*)(&wt[0][dst1]) = pb;
    }
    __syncthreads();

    const int rowA = mblk * 64 + wid * 16 + l15;
    f32x4 acc[4] = {};
    #pragma unroll 1
    for (int kk = 0; kk < 16; ++kk) {
        const int cur = kk & 1, nxt = cur ^ 1;
        float4 na, nb;
        if (kk < 15) {
            na = *(const float4*)(src0 + (kk + 1) * 32);
            nb = *(const float4*)(src1 + (kk + 1) * 32);
        }
        const bf16x8 A = *(const bf16x8*)(h_bf + rowA * TWO_D + kk * 32 + g * 8);
        bf16x8 Bf[4];
        #pragma unroll
        for (int vt = 0; vt < 4; ++vt)
            Bf[vt] = *(const bf16x8*)(&wt[cur][(vt * 16 + l15) * 40 + g * 8]);
        #pragma unroll
        for (int vt = 0; vt < 4; ++vt)
            acc[vt] = __builtin_amdgcn_mfma_f32_16x16x32_bf16(A, Bf[vt], acc[vt], 0, 0, 0);
        if (kk < 15) {
            ushort4 pa, pb;
            pa.x = f2bf(na.x); pa.y = f2bf(na.y); pa.z = f2bf(na.z); pa.w = f2bf(na.w);
            pb.x = f2bf(nb.x); pb.y = f2bf(nb.y); pb.z = f2bf(nb.z); pb.w = f2bf(nb.w);
            *(ushort4*)(&wt[nxt][dst0]) = pa;
            *(ushort4*)(&wt[nxt][dst1]) = pb;
        }
        __syncthreads();
    }

    const int rowBase = mblk * 64 + wid * 16;
    #pragma unroll
    for (int vt = 0; vt < 4; ++vt) {
        const int col = n0 + vt * 16 + l15;
        const float bias = bsrc[nloc + vt * 16 + l15];
        #pragma unroll
        for (int r = 0; r < 4; ++r) {
            const int row = rowBase + g * 4 + r;
            mv[row * TWO_D + col] = acc[vt][r] + bias;
        }
    }
}

// ---------------------------------------------------------------------------
// K_z: per-b: softplus, z, KL, ctx-logit sum. NOW writes z in MFMA-A-fragment
// packed order: zp chunk (mt*8+kk)*512 + l*8 + i  <=>  z[b=mt*16+(l&15)]
// [d=kk*32+(l>>4)*8+i], so k3's A-loads are wave-contiguous 1KB streams.
// ---------------------------------------------------------------------------
__global__ __launch_bounds__(256) void k_z(
    const int* __restrict__ center_id, const int* __restrict__ context_ids,
    const float* __restrict__ prior_means_w, const float* __restrict__ prior_vars_w,
    const float* __restrict__ vocab_W, const float* __restrict__ vocab_b,
    const float* __restrict__ epsilon, const float* __restrict__ mv,
    ushort_t* __restrict__ zp, float* __restrict__ base)
{
    __shared__ float red[8];
    __shared__ int cids[C];
    const int b = blockIdx.x, tid = threadIdx.x;
    const int cid = center_id[b];
    if (tid < C) cids[tid] = context_ids[b * C + tid];
    __syncthreads();

    const int i = tid;
    const float mean = mv[b * TWO_D + i];
    const float a    = mv[b * TWO_D + D + i];
    const float var  = softplus_f(a);
    const float z    = mean + __expf(0.5f * var) * epsilon[i];

    // packed A-fragment write
    {
        const int mt  = b >> 4;
        const int kkz = i >> 5;
        const int lz  = ((i >> 3) & 3) * 16 + (b & 15);
        zp[(mt * 8 + kkz) * 512 + lz * 8 + (i & 7)] = f2bf(z);
    }

    const float pm = prior_means_w[cid * D + i];
    const float pv = softplus_f(prior_vars_w[cid * D + i]);
    const float dm = pm - mean;
    float klt = var / pv + dm * dm / pv - 1.f + __logf(pv) - __logf(var);

    float wsum = 0.f;
    #pragma unroll
    for (int c = 0; c < C; ++c) wsum += vocab_W[cids[c] * D + i];
    float p = z * wsum;

    klt = wave_reduce(klt);
    p = wave_reduce(p);
    const int wid = tid >> 6, lane = tid & 63;
    if (lane == 0) { red[wid] = klt; red[4 + wid] = p; }
    __syncthreads();
    if (tid == 0) {
        const float kl = 0.5f * (red[0] + red[1] + red[2] + red[3]);
        float cs = red[4] + red[5] + red[6] + red[7];
        #pragma unroll
        for (int c = 0; c < C; ++c) cs += vocab_b[cids[c]];
        base[b] = cs - kl;
    }
}

// ---------------------------------------------------------------------------
// K3 (v8): fully wave-decoupled. 1-wave blocks (64 thr), grid 2084 =
// 4 rowgroups x 521 tile-groups, 3 tiles/wave. ZERO LDS, ZERO barriers.
// A preloaded from packed zp (32 x wave-contiguous 1KB, L2-hot).
// B loaded straight to registers (2 x dwordx4 contiguous per lane),
// quarter-tile (2kk, 8 loads) rotation; loads issued BEFORE a memory-clobber
// fence (cannot sink), waits are exact per-wave FIFO counts, never drained
// except at pipeline end. Epilogue exp overlaps next tile's first loads.
// ---------------------------------------------------------------------------
__global__ __launch_bounds__(64, 2) void k3_logits(
    const float* __restrict__ vocab_W, const float* __restrict__ vocab_b,
    const ushort_t* __restrict__ zp, float* __restrict__ partial)
{
    const int lane = threadIdx.x;
    const int l15 = lane & 15, g = lane >> 4;
    const int bid = blockIdx.x;
    const int gi = bid >> 2, rg = bid & 3;      // 521 groups x 4 rowgroups
    const int t0 = gi * TPB;

    // ---- A preload: 32 wave-contiguous 1KB loads from packed zp
    bf16x8 Af[4][8];
    #pragma unroll
    for (int bt = 0; bt < 4; ++bt)
        #pragma unroll
        for (int kk = 0; kk < 8; ++kk)
            Af[bt][kk] = *(const bf16x8*)(
                zp + ((((rg * 4 + bt) << 3) + kk) << 9) + (lane << 3));

    f32x4 qb[2][8];
    float bias[2][2];

#define ISSUE_Q(T, Q, BUF) do {                                               \
        _Pragma("unroll")                                                     \
        for (int _kq = 0; _kq < 2; ++_kq)                                     \
            _Pragma("unroll")                                                 \
            for (int _vt = 0; _vt < 2; ++_vt) {                               \
                const int _row = min((T) * 32 + _vt * 16 + l15, V - 1);       \
                const float* _p = vocab_W + _row * D + ((Q) * 2 + _kq) * 32 + g * 8; \
                qb[BUF][_kq * 4 + _vt * 2 + 0] = *(const f32x4*)(_p);         \
                qb[BUF][_kq * 4 + _vt * 2 + 1] = *(const f32x4*)(_p + 4);     \
            }                                                                 \
    } while (0)

#define ISSUE_BIAS(T, BUF) do {                                               \
        _Pragma("unroll")                                                     \
        for (int _vt = 0; _vt < 2; ++_vt)                                     \
            bias[BUF][_vt] = vocab_b[min((T) * 32 + _vt * 16 + l15, V - 1)];  \
    } while (0)

#define CVT8(va, vb_) ({ bf16x8 _r;                                           \
        _r[0] = (__bf16)(va)[0]; _r[1] = (__bf16)(va)[1];                     \
        _r[2] = (__bf16)(va)[2]; _r[3] = (__bf16)(va)[3];                     \
        _r[4] = (__bf16)(vb_)[0]; _r[5] = (__bf16)(vb_)[1];                   \
        _r[6] = (__bf16)(vb_)[2]; _r[7] = (__bf16)(vb_)[3]; _r; })

    float sacc[4][4] = {};

    // prologue: tile0 bias (2) + tile0 quarter0 (8)
    ISSUE_BIAS(t0, 0);
    ISSUE_Q(t0, 0, 0);
    __builtin_amdgcn_sched_barrier(0);

    #pragma unroll
    for (int i = 0; i < TPB; ++i) {
        const int t = t0 + i;
        f32x4 acc[4][2] = {};
        #pragma unroll
        for (int q = 0; q < 4; ++q) {
            const int cur = q & 1, nxt = cur ^ 1;
            if (q < 3) {
                ISSUE_Q(t, q + 1, nxt);
                SWAIT(8);           // only the just-issued 8 may remain
            } else if (i < TPB - 1) {
                ISSUE_BIAS(t + 1, (i + 1) & 1);
                ISSUE_Q(t + 1, 0, nxt);
                SWAIT(10);          // only next tile's bias(2)+q0(8) remain
            } else {
                SWAIT(0);           // pipeline end
            }
            #pragma unroll
            for (int kq = 0; kq < 2; ++kq) {
                const int kk = q * 2 + kq;
                const bf16x8 B0 = CVT8(qb[cur][kq * 4 + 0], qb[cur][kq * 4 + 1]);
                const bf16x8 B1 = CVT8(qb[cur][kq * 4 + 2], qb[cur][kq * 4 + 3]);
                #pragma unroll
                for (int bt = 0; bt < 4; ++bt) {
                    acc[bt][0] = __builtin_amdgcn_mfma_f32_16x16x32_bf16(
                        Af[bt][kk], B0, acc[bt][0], 0, 0, 0);
                    acc[bt][1] = __builtin_amdgcn_mfma_f32_16x16x32_bf16(
                        Af[bt][kk], B1, acc[bt][1], 0, 0, 0);
                }
            }
        }
        // ---- epilogue tile i (overlaps next tile's q0 flight)
        const int bb = i & 1;
        bool vld[2];
        #pragma unroll
        for (int vt = 0; vt < 2; ++vt)
            vld[vt] = (t * 32 + vt * 16 + l15) < V;
        #pragma unroll
        for (int bt = 0; bt < 4; ++bt)
            #pragma unroll
            for (int r = 0; r < 4; ++r) {
                float s = 0.f;
                #pragma unroll
                for (int vt = 0; vt < 2; ++vt)
                    s += vld[vt] ? __expf(acc[bt][vt][r] + bias[bb][vt]) : 0.f;
                sacc[bt][r] += s;
            }
    }
#undef CVT8
#undef ISSUE_BIAS
#undef ISSUE_Q

    // ---- final 16-lane reduce + single store per brow
    #pragma unroll
    for (int bt = 0; bt < 4; ++bt)
        #pragma unroll
        for (int r = 0; r < 4; ++r) {
            float s = sacc[bt][r];
            s += __shfl_xor(s, 1); s += __shfl_xor(s, 2);
            s += __shfl_xor(s, 4); s += __shfl_xor(s, 8);
            if (l15 == 0) {
                const int brow = rg * 64 + bt * 16 + g * 4 + r;
                partial[brow * NBLK_OUT + gi] = s;
            }
        }
}

// ---------------------------------------------------------------------------
// K4: per-b LSE over the NBLK_OUT partials; out_b = base_b - C*log(sum)
// ---------------------------------------------------------------------------
__global__ __launch_bounds__(256) void k4_lse(
    const float* __restrict__ partial, const float* __restrict__ base,
    float* __restrict__ outb)
{
    __shared__ float red[4];
    const int b = blockIdx.x, tid = threadIdx.x;
    float s = 0.f;
    for (int i = tid; i < NBLK_OUT; i += 256) s += partial[b * NBLK_OUT + i];
    s = wave_reduce(s);
    if ((tid & 63) == 0) red[tid >> 6] = s;
    __syncthreads();
    if (tid == 0) {
        const float tot = red[0] + red[1] + red[2] + red[3];
        outb[b] = base[b] - (float)C * __logf(tot);
    }
}

// ---------------------------------------------------------------------------
// K5: final 256 -> 1 reduce
// ---------------------------------------------------------------------------
__global__ __launch_bounds__(256) void k5_final(
    const float* __restrict__ outb, float* __restrict__ out)
{
    __shared__ float red[4];
    const int tid = threadIdx.x;
    float s = outb[tid];
    s = wave_reduce(s);
    if ((tid & 63) == 0) red[tid >> 6] = s;
    __syncthreads();
    if (tid == 0) out[0] = red[0] + red[1] + red[2] + red[3];
}

extern "C" void kernel_launch(void* const* d_in, const int* in_sizes, int n_in,
                              void* d_out, int out_size, void* d_ws, size_t ws_size,
                              hipStream_t stream)
{
    const int*   center_id     = (const int*)d_in[0];
    const int*   context_ids   = (const int*)d_in[1];
    const float* embeddings    = (const float*)d_in[2];
    const float* prior_means_w = (const float*)d_in[3];
    const float* prior_vars_w  = (const float*)d_in[4];
    const float* enc_W         = (const float*)d_in[5];
    const float* enc_b         = (const float*)d_in[6];
    const float* mean_W        = (const float*)d_in[7];
    const float* mean_b        = (const float*)d_in[8];
    const float* var_W         = (const float*)d_in[9];
    const float* var_b         = (const float*)d_in[10];
    const float* vocab_W       = (const float*)d_in[11];
    const float* vocab_b       = (const float*)d_in[12];
    const float* epsilon       = (const float*)d_in[13];

    // workspace layout (all fully rewritten every call)
    char* ws = (char*)d_ws;
    ushort_t* xbf     = (ushort_t*)ws;                            // 4 MB
    ws += (size_t)MPAD * TWO_D * 2;
    ushort_t* h_bf    = (ushort_t*)ws;                            // 256 KB
    ws += (size_t)B * TWO_D * 2;
    float*    mv      = (float*)ws;                               // 512 KB
    ws += (size_t)B * TWO_D * 4;
    ushort_t* zp      = (ushort_t*)ws;                            // 128 KB (packed z)
    ws += (size_t)B * D * 2;
    float*    base    = (float*)ws;  ws += B * 4;
    float*    outb    = (float*)ws;  ws += B * 4;
    float*    partial = (float*)ws;                               // 256*521*4 = 533 KB

    hipLaunchKernelGGL(k0_gather, dim3(2048), dim3(256), 0, stream,
                       center_id, context_ids, embeddings, xbf);
    hipLaunchKernelGGL(k_enc, dim3(512), dim3(256), 0, stream,
                       enc_W, enc_b, xbf, h_bf);
    hipLaunchKernelGGL(k_heads, dim3(32), dim3(256), 0, stream,
                       mean_W, mean_b, var_W, var_b, h_bf, mv);
    hipLaunchKernelGGL(k_z, dim3(B), dim3(256), 0, stream,
                       center_id, context_ids, prior_means_w, prior_vars_w,
                       vocab_W, vocab_b, epsilon, mv, zp, base);
    hipLaunchKernelGGL(k3_logits, dim3(4 * NGI), dim3(64), 0, stream,
                       vocab_W, vocab_b, zp, partial);
    hipLaunchKernelGGL(k4_lse, dim3(B), dim3(256), 0, stream, partial, base, outb);
    hipLaunchKernelGGL(k5_final, dim3(1), dim3(256), 0, stream, outb, (float*)d_out);
}